// Round 5
// baseline (7594.956 us; speedup 1.0000x reference)
//
#include <hip/hip_runtime.h>
#include <hip/hip_bf16.h>

#define NN 2048
#define HH 1024
#define MM 4096          // 4*H
#define NWG 128
#define TPB 256
#define NODE_CAP 8       // max nodes per batch (=> gates fit in wave0: 8*8=64)
#define CHILD_CAP 12     // max children per batch

__device__ __forceinline__ float sigmoidf_(float x) {
    return 1.0f / (1.0f + __expf(-x));
}
// fp32 -> bf16 bits (RNE), finite inputs
__device__ __forceinline__ unsigned f2bf_bits(float f) {
    unsigned u = __float_as_uint(f);
    u += 0x7fffu + ((u >> 16) & 1u);
    return u >> 16;
}
__device__ __forceinline__ float bf_bits2f(unsigned s) {
    return __uint_as_float(s << 16);
}

// ---------------------------------------------------------------- init flags
__global__ void init_flags(int* flags) {
    if (threadIdx.x < NWG) flags[threadIdx.x] = -1;
}

// ---------------------------------------------------------------- scheduler
// Levels (level[t] = 0 leaves, else 1+max child level; children of t are
// j in [t-8,t-1] with par[j]==t), counting-sort by level (stable), THEN the
// full batch schedule: batches of <=NODE_CAP nodes / <=CHILD_CAP children,
// per batch a packed slot list (old children first, then fresh = level r-1),
// header packed in 2 ints. All static -- computed once here, not per-WG.
__global__ void build_sched(const int* __restrict__ parent_g,
                            int* __restrict__ order,   // [NN]
                            int* __restrict__ meta,    // [0]=nlv [1]=n0 [2]=nbt
                            int* __restrict__ bhdr,    // [2*NN]
                            int* __restrict__ slots)   // [NN]
{
    __shared__ int par[NN];
    __shared__ int lvl[NN];
    __shared__ int cnt[NN + 1];
    __shared__ int off_l[NN + 1];
    __shared__ int order_l[NN];
    const int tid = threadIdx.x;
    for (int i = tid; i < NN; i += TPB) par[i] = parent_g[i];
    for (int i = tid; i <= NN; i += TPB) cnt[i] = 0;
    __syncthreads();
    if (tid == 0) {
        int lm1 = 0, lm2 = 0, lm3 = 0, lm4 = 0, lm5 = 0, lm6 = 0, lm7 = 0, lm8 = 0;
        int maxl = 0;
        for (int t = 0; t < NN; ++t) {
            int l = -1;
            if (t >= 1 && par[t - 1] == t && lm1 > l) l = lm1;
            if (t >= 2 && par[t - 2] == t && lm2 > l) l = lm2;
            if (t >= 3 && par[t - 3] == t && lm3 > l) l = lm3;
            if (t >= 4 && par[t - 4] == t && lm4 > l) l = lm4;
            if (t >= 5 && par[t - 5] == t && lm5 > l) l = lm5;
            if (t >= 6 && par[t - 6] == t && lm6 > l) l = lm6;
            if (t >= 7 && par[t - 7] == t && lm7 > l) l = lm7;
            if (t >= 8 && par[t - 8] == t && lm8 > l) l = lm8;
            ++l;
            lvl[t] = l;
            cnt[l]++;
            if (l > maxl) maxl = l;
            lm8 = lm7; lm7 = lm6; lm6 = lm5; lm5 = lm4;
            lm4 = lm3; lm3 = lm2; lm2 = lm1; lm1 = l;
        }
        int run = 0;
        for (int l = 0; l <= maxl; ++l) {
            const int c = cnt[l];
            cnt[l] = run;
            off_l[l] = run;
            run += c;
        }
        off_l[maxl + 1] = run;
        const int nlv = maxl + 1;
        for (int t = 0; t < NN; ++t)
            order_l[cnt[lvl[t]]++] = t;   // stable: ascending node id per level

        // ---- batch schedule
        int nbt = 0, sp = 0;
        for (int r = 1; r < nlv; ++r) {
            int i = off_l[r];
            const int e = off_l[r + 1];
            while (i < e) {
                const int ns = i;
                int nc = 0, oc = 0, fc = 0;
                const int ss = sp;
                while (i < e && nc < NODE_CAP) {
                    const int t = order_l[i];
                    const int lo = t >= 8 ? t - 8 : 0;
                    int k = 0;
                    for (int j = lo; j < t; ++j) k += (par[j] == t);
                    if (nc > 0 && oc + fc + k > CHILD_CAP) break;
                    for (int j = lo; j < t; ++j)
                        if (par[j] == t) { if (lvl[j] == r - 1) ++fc; else ++oc; }
                    ++nc; ++i;
                }
                int op = ss, fp = ss + oc;
                for (int q = 0; q < nc; ++q) {
                    const int t = order_l[ns + q];
                    const int lo = t >= 8 ? t - 8 : 0;
                    for (int j = lo; j < t; ++j) {
                        if (par[j] != t) continue;
                        const int pk = (q << 12) | j;
                        if (lvl[j] == r - 1) slots[fp++] = pk;
                        else                 slots[op++] = pk;
                    }
                }
                sp = fp;
                const int lastb = (i >= e) ? 1 : 0;
                bhdr[2 * nbt]     = ns | (nc << 12) | (oc << 16) | (fc << 21)
                                       | (lastb << 26);
                bhdr[2 * nbt + 1] = ss | (r << 12);
                ++nbt;
            }
        }
        meta[0] = nlv;
        meta[1] = off_l[1];   // leaf count
        meta[2] = nbt;
    }
    __syncthreads();
    for (int i = tid; i < NN; i += TPB) order[i] = order_l[i];
}

// ---------------------------------------------------------------- gx GEMM
// gx[n][m] = sum_d emb[inputs[n]][d] * Wx[m][d] + bx[m]   (m = g*1024+h)
__global__ void __launch_bounds__(256) gx_gemm(
    const int* __restrict__ idx, const float* __restrict__ emb,
    const float* __restrict__ Wx, const float* __restrict__ bx,
    unsigned short* __restrict__ gx)
{
    __shared__ float As[16][64];
    __shared__ float Bs[16][64];
    const int tid = threadIdx.x;
    const int tx = tid & 15, ty = tid >> 4;
    const int mt = blockIdx.x, nt = blockIdx.y;
    const int lrow = tid >> 2;            // 0..63
    const int lk   = (tid & 3) << 2;      // 0,4,8,12
    const int gn = nt * 64 + lrow;
    const int gm = mt * 64 + lrow;
    const float* arow = emb + (size_t)idx[gn] * HH;
    const float* wrow = Wx + (size_t)gm * HH;
    float acc[4][4] = {};
    for (int k0 = 0; k0 < HH; k0 += 16) {
        float4 av = *(const float4*)(arow + k0 + lk);
        float4 wv = *(const float4*)(wrow + k0 + lk);
        __syncthreads();
        As[lk + 0][lrow] = av.x; As[lk + 1][lrow] = av.y;
        As[lk + 2][lrow] = av.z; As[lk + 3][lrow] = av.w;
        Bs[lk + 0][lrow] = wv.x; Bs[lk + 1][lrow] = wv.y;
        Bs[lk + 2][lrow] = wv.z; Bs[lk + 3][lrow] = wv.w;
        __syncthreads();
        #pragma unroll
        for (int k = 0; k < 16; ++k) {
            const float4 a = *(const float4*)&As[k][ty * 4];
            const float4 b = *(const float4*)&Bs[k][tx * 4];
            const float aa[4] = {a.x, a.y, a.z, a.w};
            const float bb[4] = {b.x, b.y, b.z, b.w};
            #pragma unroll
            for (int i = 0; i < 4; ++i)
                #pragma unroll
                for (int j = 0; j < 4; ++j)
                    acc[i][j] += aa[i] * bb[j];
        }
    }
    #pragma unroll
    for (int i = 0; i < 4; ++i) {
        const int gr = nt * 64 + ty * 4 + i;
        #pragma unroll
        for (int j = 0; j < 4; ++j) {
            const int gc = mt * 64 + tx * 4 + j;
            gx[(size_t)gr * MM + gc] = (unsigned short)f2bf_bits(acc[i][j] + bx[gc]);
        }
    }
}

// ---------------------------------------------------------------- tree scan
// Precomputed batch schedule; per batch:
//   phase A: gx load + dpart zero (double-buffered) -> B1
//   old dots: direct-global h reads (visibility from previous level's acquire)
//   wait flags >= r-1 (overlapped by phase A + old dots) -> B2
//   fresh dots: direct-global h reads -> B3
//   wave0 ONLY: gates, h stores, wave-level vmcnt drain, release publish.
//   Waves 1-3 run ahead into next batch's phase A (no trailing barrier).
// c state: 64 KB dynamic LDS c_all[NN][8], WG-owned.
__global__ void __launch_bounds__(TPB, 1) lstm_scan(
    const float* __restrict__ Wh,
    const float* __restrict__ bh,
    const unsigned short* __restrict__ gx,   // bf16 bits [N][4][H]
    const int* __restrict__ order_g,
    const int* __restrict__ meta_g,
    const int* __restrict__ bhdr_g,
    const int* __restrict__ slots_g,
    int* flags,
    float* out)   // fp32: [ hs (NN*HH) | c_root (HH) | h_root (HH) ]
{
    extern __shared__ float c_all[];   // [NN*8] = 64 KB dynamic LDS

    const int b      = blockIdx.x;
    const int tid    = threadIdx.x;
    const int e_loc  = tid >> 5;       // 0..7
    const int lane32 = tid & 31;

    __shared__ int   order_s[NN];             // 8 KB
    __shared__ int   slots_s[NN];             // 8 KB
    __shared__ int   bhdr_s[2 * NN];          // 16 KB
    __shared__ float gx_st[2][NODE_CAP][4][8];// 2 KB  (double-buffered)
    __shared__ float dpart[2][NODE_CAP][4][8];// 2 KB  (double-buffered)
    __shared__ float bh_s[4][8];              // 128 B
    __shared__ int   meta_s[4];

    if (tid < 3) meta_s[tid] = meta_g[tid];
    for (int i = tid; i < NN; i += TPB) { order_s[i] = order_g[i]; slots_s[i] = slots_g[i]; }
    for (int i = tid; i < 2 * NN; i += TPB) bhdr_s[i] = bhdr_g[i];
    if (tid < 32)
        bh_s[tid >> 3][tid & 7] = bh[(size_t)(tid >> 3) * HH + b * 8 + (tid & 7)];

    float w_i[32], w_o[32], w_u[32], w_f[32];
    {
        const int e_glob = b * 8 + e_loc;
        const float* wi = Wh + ((size_t)(0 * HH + e_glob)) * HH + lane32;
        const float* wo = Wh + ((size_t)(1 * HH + e_glob)) * HH + lane32;
        const float* wu = Wh + ((size_t)(2 * HH + e_glob)) * HH + lane32;
        const float* wf = Wh + ((size_t)(3 * HH + e_glob)) * HH + lane32;
        #pragma unroll
        for (int s = 0; s < 32; ++s) {
            w_i[s] = wi[s * 32];
            w_o[s] = wo[s * 32];
            w_u[s] = wu[s * 32];
            w_f[s] = wf[s * 32];
        }
    }
    const float bhf = bh[3 * HH + b * 8 + e_loc];
    __syncthreads();

    const int n0  = meta_s[1];
    const int nbt = meta_s[2];
    int seen = -1;   // cached monotone lower bound of flags[tid] (tid < NWG)

    // ---- round 0: all leaves, elementwise-parallel, no cross-WG data
    {
        for (int base = 0; base < n0; base += 32) {
            const int i = base + (tid >> 3);
            if (i < n0) {
                const int t = order_s[i];
                const int e = tid & 7;
                const size_t g0 = (size_t)t * MM + b * 8 + e;
                const float iv = sigmoidf_(bf_bits2f(gx[g0]) + bh_s[0][e]);
                const float ov = sigmoidf_(bf_bits2f(gx[g0 + HH]) + bh_s[1][e]);
                const float uv = tanhf(bf_bits2f(gx[g0 + 2 * HH]) + bh_s[2][e]);
                const float c  = iv * uv;
                const float h  = ov * tanhf(c);
                c_all[t * 8 + e] = c;
                __hip_atomic_store(out + (size_t)t * HH + b * 8 + e, h,
                                   __ATOMIC_RELAXED, __HIP_MEMORY_SCOPE_AGENT);
            }
        }
        __syncthreads();   // drains vmcnt -> h stores globally visible
        if (tid == 0)
            __hip_atomic_store(&flags[b], 0, __ATOMIC_RELEASE,
                               __HIP_MEMORY_SCOPE_AGENT);
    }

    // ---- batches (levels 1..nlv-1, precomputed)
    int pb = 0;
    for (int bt = 0; bt < nbt; ++bt) {
        const int A  = bhdr_s[2 * bt];
        const int B  = bhdr_s[2 * bt + 1];
        const int ns = A & 0xFFF;
        const int nc = (A >> 12) & 0xF;
        const int oc = (A >> 16) & 0x1F;
        const int fc = (A >> 21) & 0x1F;
        const int lastb = (A >> 26) & 1;
        const int ss = B & 0xFFF;
        const int r  = (B >> 12) & 0x7FF;

        // -- phase A: gx + dpart zero into buffer pb (concurrent with wave0's
        //    gates of the previous batch, which use buffer pb^1... note pb
        //    already flipped at end of loop, so prev batch used pb^1).
        if (tid < nc * 32) {
            const int n = tid >> 5, g = (tid >> 3) & 3, e = tid & 7;
            gx_st[pb][n][g][e] =
                bf_bits2f(gx[(size_t)order_s[ns + n] * MM + g * HH + b * 8 + e]);
            dpart[pb][n][g][e] = 0.0f;
        }
        __syncthreads();   // B1 (rejoin point for wave0 after publish)

        // -- old-child dots, direct from global (levels <= r-2: visibility
        //    guaranteed by the acquire at level r-1's wait)
        for (int s = 0; s < oc; ++s) {
            const int pk = slots_s[ss + s];
            const int j = pk & 0xFFF, n = pk >> 12;
            const float* hrow = out + (size_t)j * HH + lane32;
            float d0 = 0.0f, d1 = 0.0f, d2 = 0.0f, d3 = 0.0f;
            #pragma unroll
            for (int q = 0; q < 32; ++q) {
                const float hv = __hip_atomic_load(hrow + 32 * q, __ATOMIC_RELAXED,
                                                   __HIP_MEMORY_SCOPE_AGENT);
                d0 += w_i[q] * hv; d1 += w_o[q] * hv;
                d2 += w_u[q] * hv; d3 += w_f[q] * hv;
            }
            #pragma unroll
            for (int o2 = 16; o2 > 0; o2 >>= 1) {
                d0 += __shfl_down(d0, o2, 32); d1 += __shfl_down(d1, o2, 32);
                d2 += __shfl_down(d2, o2, 32); d3 += __shfl_down(d3, o2, 32);
            }
            if (lane32 == 0) {
                dpart[pb][n][0][e_loc] += d0;
                dpart[pb][n][1][e_loc] += d1;
                dpart[pb][n][2][e_loc] += d2;
                dpart[pb][n][3][e_loc] +=
                    sigmoidf_(gx_st[pb][n][3][e_loc] + d3 + bhf)
                    * c_all[j * 8 + e_loc];
            }
        }

        // -- tight wait for level r-1 publications (overlapped by the above)
        if (tid < NWG && seen < r - 1) {
            int v;
            while ((v = __hip_atomic_load(&flags[tid], __ATOMIC_ACQUIRE,
                                          __HIP_MEMORY_SCOPE_AGENT)) < r - 1)
                __builtin_amdgcn_s_sleep(1);
            seen = v;
        }
        __syncthreads();   // B2

        // -- fresh-child dots, direct from global
        for (int s = 0; s < fc; ++s) {
            const int pk = slots_s[ss + oc + s];
            const int j = pk & 0xFFF, n = pk >> 12;
            const float* hrow = out + (size_t)j * HH + lane32;
            float d0 = 0.0f, d1 = 0.0f, d2 = 0.0f, d3 = 0.0f;
            #pragma unroll
            for (int q = 0; q < 32; ++q) {
                const float hv = __hip_atomic_load(hrow + 32 * q, __ATOMIC_RELAXED,
                                                   __HIP_MEMORY_SCOPE_AGENT);
                d0 += w_i[q] * hv; d1 += w_o[q] * hv;
                d2 += w_u[q] * hv; d3 += w_f[q] * hv;
            }
            #pragma unroll
            for (int o2 = 16; o2 > 0; o2 >>= 1) {
                d0 += __shfl_down(d0, o2, 32); d1 += __shfl_down(d1, o2, 32);
                d2 += __shfl_down(d2, o2, 32); d3 += __shfl_down(d3, o2, 32);
            }
            if (lane32 == 0) {
                dpart[pb][n][0][e_loc] += d0;
                dpart[pb][n][1][e_loc] += d1;
                dpart[pb][n][2][e_loc] += d2;
                dpart[pb][n][3][e_loc] +=
                    sigmoidf_(gx_st[pb][n][3][e_loc] + d3 + bhf)
                    * c_all[j * 8 + e_loc];
            }
        }
        __syncthreads();   // B3: dpart complete

        // -- gates on wave0 only; slim publish (no full-WG barrier)
        if (tid < 64) {
            if (tid < nc * 8) {
                const int n = tid >> 3, e = tid & 7;
                const int t = order_s[ns + n];
                const float iv = sigmoidf_(gx_st[pb][n][0][e] + dpart[pb][n][0][e] + bh_s[0][e]);
                const float ov = sigmoidf_(gx_st[pb][n][1][e] + dpart[pb][n][1][e] + bh_s[1][e]);
                const float uv = tanhf    (gx_st[pb][n][2][e] + dpart[pb][n][2][e] + bh_s[2][e]);
                const float c  = iv * uv + dpart[pb][n][3][e];
                const float h  = ov * tanhf(c);
                c_all[t * 8 + e] = c;
                __hip_atomic_store(out + (size_t)t * HH + b * 8 + e, h,
                                   __ATOMIC_RELAXED, __HIP_MEMORY_SCOPE_AGENT);
                if (t == NN - 1) {
                    __hip_atomic_store(out + (size_t)NN * HH + b * 8 + e, c,
                                       __ATOMIC_RELAXED, __HIP_MEMORY_SCOPE_AGENT);
                    __hip_atomic_store(out + (size_t)NN * HH + HH + b * 8 + e, h,
                                       __ATOMIC_RELAXED, __HIP_MEMORY_SCOPE_AGENT);
                }
            }
            // wave-shared vmcnt covers all wave0 lanes' h stores
            asm volatile("s_waitcnt vmcnt(0)" ::: "memory");
            if (tid == 0 && lastb)
                __hip_atomic_store(&flags[b], r, __ATOMIC_RELEASE,
                                   __HIP_MEMORY_SCOPE_AGENT);
        }
        // no barrier: waves 1-3 proceed to next batch's phase A (buffer pb^1)
        pb ^= 1;
    }
}

// ---------------------------------------------------------------- launch
extern "C" void kernel_launch(void* const* d_in, const int* in_sizes, int n_in,
                              void* d_out, int out_size, void* d_ws, size_t ws_size,
                              hipStream_t stream)
{
    const int*   inputs = (const int*)d_in[0];
    const int*   parent = (const int*)d_in[1];
    const float* emb    = (const float*)d_in[2];
    const float* Wx     = (const float*)d_in[3];
    const float* bx     = (const float*)d_in[4];
    const float* Wh     = (const float*)d_in[5];
    const float* bh     = (const float*)d_in[6];
    float* out = (float*)d_out;          // fp32 output (reference is fp32)

    char* ws = (char*)d_ws;
    int*  flags = (int*)ws;                                     // 512 B
    unsigned short* gx = (unsigned short*)(ws + 1024);          // 16 MB bf16
    char* ws2 = ws + 1024 + (size_t)NN * MM * 2;
    int*  order = (int*)ws2;                                    // 8 KB
    int*  meta  = (int*)(ws2 + 8192);                           // 64 B
    int*  bhdr  = (int*)(ws2 + 8192 + 64);                      // 16 KB
    int*  slots = (int*)(ws2 + 8192 + 64 + 16384);              // 8 KB

    // dynamic LDS: c_all 64 KB (static ~37 KB => ~101 KB total)
    hipFuncSetAttribute(reinterpret_cast<const void*>(lstm_scan),
                        hipFuncAttributeMaxDynamicSharedMemorySize, 65536);

    hipLaunchKernelGGL(init_flags, dim3(1), dim3(128), 0, stream, flags);
    hipLaunchKernelGGL(build_sched, dim3(1), dim3(TPB), 0, stream,
                       parent, order, meta, bhdr, slots);
    hipLaunchKernelGGL(gx_gemm, dim3(MM / 64, NN / 64), dim3(256), 0, stream,
                       inputs, emb, Wx, bx, gx);
    hipLaunchKernelGGL(lstm_scan, dim3(NWG), dim3(TPB), 65536, stream,
                       Wh, bh, gx, order, meta, bhdr, slots, flags, out);
}

// Round 7
// 4995.324 us; speedup vs baseline: 1.5204x; 1.5204x over previous
//
#include <hip/hip_runtime.h>
#include <hip/hip_bf16.h>

#define NN 2048
#define HH 1024
#define MM 4096          // 4*H
#define NWG 128
#define TPB 256
#define NODE_CAP 8       // max nodes per batch (=> gates fit in wave0: 8*8=64)
#define CHILD_CAP 12     // max children per batch

__device__ __forceinline__ float sigmoidf_(float x) {
    return 1.0f / (1.0f + __expf(-x));
}
// fp32 -> bf16 bits (RNE), finite inputs
__device__ __forceinline__ unsigned f2bf_bits(float f) {
    unsigned u = __float_as_uint(f);
    u += 0x7fffu + ((u >> 16) & 1u);
    return u >> 16;
}
__device__ __forceinline__ float bf_bits2f(unsigned s) {
    return __uint_as_float(s << 16);
}

// ---------------------------------------------------------------- init flags
__global__ void init_flags(int* flags) {
    if (threadIdx.x < NWG) flags[threadIdx.x] = -1;
}

// ---------------------------------------------------------------- scheduler
// Parallelized (R5's tid0-serial batch build was ~2.8 ms). Serial parts kept:
// the level chain (true dependence, register rolling window) and two short
// prefix sums. Everything else parallel. Within-level node order NON-STABLE
// (atomic scatter): numerically irrelevant -- each node keeps all its
// children (packed ascending j) in one batch; nodes independent given
// children. Output format unchanged.
// R6 bug fixed: static LDS was 65548 B > 64 KB cap (compile failure).
// nbb/ssb now ALIAS dead arrays (cnt after scatter, par after msk build);
// static total now 49164 B.
__global__ void build_sched(const int* __restrict__ parent_g,
                            int* __restrict__ order,   // [NN]
                            int* __restrict__ meta,    // [0]=nlv [1]=n0 [2]=nbt
                            int* __restrict__ bhdr,    // [2*NN]
                            int* __restrict__ slots)   // [NN]
{
    __shared__ int par[NN];
    __shared__ int msk[NN];
    __shared__ int lvl[NN];
    __shared__ int cnt[NN + 1];
    __shared__ int off_l[NN + 1];
    __shared__ int order_l[NN];
    __shared__ int nlv_sh;
    // aliases over dead storage (see note above):
    int* nbb = cnt;   // per-level batch count -> base (cnt dead after scatter)
    int* ssb = par;   // per-level slot count -> base (par dead after msk build)
    const int tid = threadIdx.x;

    for (int i = tid; i < NN; i += TPB) par[i] = parent_g[i];
    for (int i = tid; i <= NN; i += TPB) cnt[i] = 0;
    __syncthreads();
    // child bitmask: bit (d-1) set iff par[t-d]==t  (children = t-8..t-1)
    for (int t = tid; t < NN; t += TPB) {
        int m = 0;
        #pragma unroll
        for (int d = 1; d <= 8; ++d) {
            const int j = t - d;
            if (j >= 0 && par[j] == t) m |= 1 << (d - 1);
        }
        msk[t] = m;
    }
    __syncthreads();   // par dead from here (ssb may overwrite)
    // level chain: the only true serial dependence; registers + 1 LDS read/iter
    if (tid == 0) {
        int l1 = 0, l2 = 0, l3 = 0, l4 = 0, l5 = 0, l6 = 0, l7 = 0, l8 = 0;
        int maxl = 0;
        for (int t = 0; t < NN; ++t) {
            const int m = msk[t];
            int l = -1;
            if (m & 1)   l = l1 > l ? l1 : l;
            if (m & 2)   l = l2 > l ? l2 : l;
            if (m & 4)   l = l3 > l ? l3 : l;
            if (m & 8)   l = l4 > l ? l4 : l;
            if (m & 16)  l = l5 > l ? l5 : l;
            if (m & 32)  l = l6 > l ? l6 : l;
            if (m & 64)  l = l7 > l ? l7 : l;
            if (m & 128) l = l8 > l ? l8 : l;
            ++l;
            lvl[t] = l;
            if (l > maxl) maxl = l;
            l8 = l7; l7 = l6; l6 = l5; l5 = l4;
            l4 = l3; l3 = l2; l2 = l1; l1 = l;
        }
        nlv_sh = maxl + 1;
    }
    __syncthreads();
    const int nlv = nlv_sh;
    // histogram (parallel, LDS atomics)
    for (int t = tid; t < NN; t += TPB) atomicAdd(&cnt[lvl[t]], 1);
    __syncthreads();
    if (tid == 0) {
        int run = 0;
        for (int l = 0; l < nlv; ++l) {
            const int c = cnt[l];
            off_l[l] = run; cnt[l] = run;   // cnt becomes scatter cursor
            run += c;
        }
        off_l[nlv] = run;   // == NN
    }
    __syncthreads();
    // non-stable scatter into level buckets
    for (int t = tid; t < NN; t += TPB)
        order_l[atomicAdd(&cnt[lvl[t]], 1)] = t;
    __syncthreads();   // cnt dead from here (nbb may overwrite)
    // pass 1: per-level batch & slot counts (levels independent -> parallel)
    for (int l = 1 + tid; l < nlv; l += TPB) {
        const int s1 = off_l[l + 1];
        int i = off_l[l], nb = 0, sl = 0;
        while (i < s1) {
            int nc = 0, cc = 0;
            while (i < s1 && nc < NODE_CAP) {
                const int k = __popc(msk[order_l[i]]);
                if (nc > 0 && cc + k > CHILD_CAP) break;
                cc += k; ++nc; ++i;
            }
            sl += cc; ++nb;
        }
        nbb[l] = nb; ssb[l] = sl;
    }
    __syncthreads();
    if (tid == 0) {
        int br = 0, sr = 0;
        for (int l = 1; l < nlv; ++l) {
            const int nb = nbb[l], sl = ssb[l];
            nbb[l] = br; ssb[l] = sr;
            br += nb; sr += sl;
        }
        meta[0] = nlv;
        meta[1] = off_l[1];   // leaf count
        meta[2] = br;         // total batches
    }
    __syncthreads();
    // pass 2: fill bhdr + slots (same greedy as pass 1 -> identical batches)
    for (int l = 1 + tid; l < nlv; l += TPB) {
        const int s1 = off_l[l + 1];
        int i = off_l[l];
        int bi = nbb[l], sp = ssb[l];
        while (i < s1) {
            const int ns_ord = i;
            int nc = 0, cc = 0;
            while (i < s1 && nc < NODE_CAP) {
                const int k = __popc(msk[order_l[i]]);
                if (nc > 0 && cc + k > CHILD_CAP) break;
                cc += k; ++nc; ++i;
            }
            int oc = 0;
            for (int q = 0; q < nc; ++q) {
                const int t = order_l[ns_ord + q];
                const int m = msk[t];
                for (int d = 8; d >= 1; --d)
                    if (m & (1 << (d - 1)))
                        oc += (lvl[t - d] != l - 1);
            }
            const int fcv = cc - oc;
            const int sb = sp;
            int op = sb, fp = sb + oc;
            for (int q = 0; q < nc; ++q) {
                const int t = order_l[ns_ord + q];
                const int m = msk[t];
                for (int d = 8; d >= 1; --d)      // j ascending
                    if (m & (1 << (d - 1))) {
                        const int j = t - d;
                        const int pk = (q << 12) | j;
                        if (lvl[j] == l - 1) slots[fp++] = pk;
                        else                 slots[op++] = pk;
                    }
            }
            sp = sb + cc;
            const int lastb = (i >= s1) ? 1 : 0;
            bhdr[2 * bi]     = ns_ord | (nc << 12) | (oc << 16) | (fcv << 21)
                                      | (lastb << 26);
            bhdr[2 * bi + 1] = sb | (l << 12);
            ++bi;
        }
    }
    __syncthreads();
    for (int i = tid; i < NN; i += TPB) order[i] = order_l[i];
}

// ---------------------------------------------------------------- gx GEMM
// gx[n][m] = sum_d emb[inputs[n]][d] * Wx[m][d] + bx[m]   (m = g*1024+h)
__global__ void __launch_bounds__(256) gx_gemm(
    const int* __restrict__ idx, const float* __restrict__ emb,
    const float* __restrict__ Wx, const float* __restrict__ bx,
    unsigned short* __restrict__ gx)
{
    __shared__ float As[16][64];
    __shared__ float Bs[16][64];
    const int tid = threadIdx.x;
    const int tx = tid & 15, ty = tid >> 4;
    const int mt = blockIdx.x, nt = blockIdx.y;
    const int lrow = tid >> 2;            // 0..63
    const int lk   = (tid & 3) << 2;      // 0,4,8,12
    const int gn = nt * 64 + lrow;
    const int gm = mt * 64 + lrow;
    const float* arow = emb + (size_t)idx[gn] * HH;
    const float* wrow = Wx + (size_t)gm * HH;
    float acc[4][4] = {};
    for (int k0 = 0; k0 < HH; k0 += 16) {
        float4 av = *(const float4*)(arow + k0 + lk);
        float4 wv = *(const float4*)(wrow + k0 + lk);
        __syncthreads();
        As[lk + 0][lrow] = av.x; As[lk + 1][lrow] = av.y;
        As[lk + 2][lrow] = av.z; As[lk + 3][lrow] = av.w;
        Bs[lk + 0][lrow] = wv.x; Bs[lk + 1][lrow] = wv.y;
        Bs[lk + 2][lrow] = wv.z; Bs[lk + 3][lrow] = wv.w;
        __syncthreads();
        #pragma unroll
        for (int k = 0; k < 16; ++k) {
            const float4 a = *(const float4*)&As[k][ty * 4];
            const float4 b = *(const float4*)&Bs[k][tx * 4];
            const float aa[4] = {a.x, a.y, a.z, a.w};
            const float bb[4] = {b.x, b.y, b.z, b.w};
            #pragma unroll
            for (int i = 0; i < 4; ++i)
                #pragma unroll
                for (int j = 0; j < 4; ++j)
                    acc[i][j] += aa[i] * bb[j];
        }
    }
    #pragma unroll
    for (int i = 0; i < 4; ++i) {
        const int gr = nt * 64 + ty * 4 + i;
        #pragma unroll
        for (int j = 0; j < 4; ++j) {
            const int gc = mt * 64 + tx * 4 + j;
            gx[(size_t)gr * MM + gc] = (unsigned short)f2bf_bits(acc[i][j] + bx[gc]);
        }
    }
}

// ---------------------------------------------------------------- tree scan
// Precomputed batch schedule; per batch:
//   phase A: gx load + dpart zero (double-buffered) -> B1
//   old dots: direct-global h reads (visibility from previous level's acquire)
//   wait flags >= r-1 (relaxed poll, single final acquire) -> B2
//   fresh dots: direct-global h reads -> B3
//   wave0 ONLY: gates, h stores, wave-level vmcnt drain, release publish.
//   Waves 1-3 run ahead into next batch's phase A (no trailing barrier).
// c state: 64 KB dynamic LDS c_all[NN][8], WG-owned.
__global__ void __launch_bounds__(TPB, 1) lstm_scan(
    const float* __restrict__ Wh,
    const float* __restrict__ bh,
    const unsigned short* __restrict__ gx,   // bf16 bits [N][4][H]
    const int* __restrict__ order_g,
    const int* __restrict__ meta_g,
    const int* __restrict__ bhdr_g,
    const int* __restrict__ slots_g,
    int* flags,
    float* out)   // fp32: [ hs (NN*HH) | c_root (HH) | h_root (HH) ]
{
    extern __shared__ float c_all[];   // [NN*8] = 64 KB dynamic LDS

    const int b      = blockIdx.x;
    const int tid    = threadIdx.x;
    const int e_loc  = tid >> 5;       // 0..7
    const int lane32 = tid & 31;

    __shared__ int   order_s[NN];             // 8 KB
    __shared__ int   slots_s[NN];             // 8 KB
    __shared__ int   bhdr_s[2 * NN];          // 16 KB
    __shared__ float gx_st[2][NODE_CAP][4][8];// 2 KB  (double-buffered)
    __shared__ float dpart[2][NODE_CAP][4][8];// 2 KB  (double-buffered)
    __shared__ float bh_s[4][8];              // 128 B
    __shared__ int   meta_s[4];

    if (tid < 3) meta_s[tid] = meta_g[tid];
    for (int i = tid; i < NN; i += TPB) { order_s[i] = order_g[i]; slots_s[i] = slots_g[i]; }
    for (int i = tid; i < 2 * NN; i += TPB) bhdr_s[i] = bhdr_g[i];
    if (tid < 32)
        bh_s[tid >> 3][tid & 7] = bh[(size_t)(tid >> 3) * HH + b * 8 + (tid & 7)];

    float w_i[32], w_o[32], w_u[32], w_f[32];
    {
        const int e_glob = b * 8 + e_loc;
        const float* wi = Wh + ((size_t)(0 * HH + e_glob)) * HH + lane32;
        const float* wo = Wh + ((size_t)(1 * HH + e_glob)) * HH + lane32;
        const float* wu = Wh + ((size_t)(2 * HH + e_glob)) * HH + lane32;
        const float* wf = Wh + ((size_t)(3 * HH + e_glob)) * HH + lane32;
        #pragma unroll
        for (int s = 0; s < 32; ++s) {
            w_i[s] = wi[s * 32];
            w_o[s] = wo[s * 32];
            w_u[s] = wu[s * 32];
            w_f[s] = wf[s * 32];
        }
    }
    const float bhf = bh[3 * HH + b * 8 + e_loc];
    __syncthreads();

    const int n0  = meta_s[1];
    const int nbt = meta_s[2];
    int seen = -1;   // cached monotone lower bound of flags[tid] (tid < NWG)

    // ---- round 0: all leaves, elementwise-parallel, no cross-WG data
    {
        for (int base = 0; base < n0; base += 32) {
            const int i = base + (tid >> 3);
            if (i < n0) {
                const int t = order_s[i];
                const int e = tid & 7;
                const size_t g0 = (size_t)t * MM + b * 8 + e;
                const float iv = sigmoidf_(bf_bits2f(gx[g0]) + bh_s[0][e]);
                const float ov = sigmoidf_(bf_bits2f(gx[g0 + HH]) + bh_s[1][e]);
                const float uv = tanhf(bf_bits2f(gx[g0 + 2 * HH]) + bh_s[2][e]);
                const float c  = iv * uv;
                const float h  = ov * tanhf(c);
                c_all[t * 8 + e] = c;
                __hip_atomic_store(out + (size_t)t * HH + b * 8 + e, h,
                                   __ATOMIC_RELAXED, __HIP_MEMORY_SCOPE_AGENT);
            }
        }
        __syncthreads();   // drains vmcnt -> h stores globally visible
        if (tid == 0)
            __hip_atomic_store(&flags[b], 0, __ATOMIC_RELEASE,
                               __HIP_MEMORY_SCOPE_AGENT);
    }

    // ---- batches (levels 1..nlv-1, precomputed)
    int pb = 0;
    for (int bt = 0; bt < nbt; ++bt) {
        const int A  = bhdr_s[2 * bt];
        const int B  = bhdr_s[2 * bt + 1];
        const int ns = A & 0xFFF;
        const int nc = (A >> 12) & 0xF;
        const int oc = (A >> 16) & 0x1F;
        const int fc = (A >> 21) & 0x1F;
        const int lastb = (A >> 26) & 1;
        const int ss = B & 0xFFF;
        const int r  = (B >> 12) & 0x7FF;

        // -- phase A: gx + dpart zero into buffer pb
        if (tid < nc * 32) {
            const int n = tid >> 5, g = (tid >> 3) & 3, e = tid & 7;
            gx_st[pb][n][g][e] =
                bf_bits2f(gx[(size_t)order_s[ns + n] * MM + g * HH + b * 8 + e]);
            dpart[pb][n][g][e] = 0.0f;
        }
        __syncthreads();   // B1 (rejoin point for wave0 after publish)

        // -- old-child dots, direct from global (levels <= r-2: visibility
        //    guaranteed by the acquire at level r-1's wait)
        for (int s = 0; s < oc; ++s) {
            const int pk = slots_s[ss + s];
            const int j = pk & 0xFFF, n = pk >> 12;
            const float* hrow = out + (size_t)j * HH + lane32;
            float d0 = 0.0f, d1 = 0.0f, d2 = 0.0f, d3 = 0.0f;
            #pragma unroll
            for (int q = 0; q < 32; ++q) {
                const float hv = __hip_atomic_load(hrow + 32 * q, __ATOMIC_RELAXED,
                                                   __HIP_MEMORY_SCOPE_AGENT);
                d0 += w_i[q] * hv; d1 += w_o[q] * hv;
                d2 += w_u[q] * hv; d3 += w_f[q] * hv;
            }
            #pragma unroll
            for (int o2 = 16; o2 > 0; o2 >>= 1) {
                d0 += __shfl_down(d0, o2, 32); d1 += __shfl_down(d1, o2, 32);
                d2 += __shfl_down(d2, o2, 32); d3 += __shfl_down(d3, o2, 32);
            }
            if (lane32 == 0) {
                dpart[pb][n][0][e_loc] += d0;
                dpart[pb][n][1][e_loc] += d1;
                dpart[pb][n][2][e_loc] += d2;
                dpart[pb][n][3][e_loc] +=
                    sigmoidf_(gx_st[pb][n][3][e_loc] + d3 + bhf)
                    * c_all[j * 8 + e_loc];
            }
        }

        // -- tight wait for level r-1 (relaxed poll + single final acquire)
        if (tid < NWG && seen < r - 1) {
            while (__hip_atomic_load(&flags[tid], __ATOMIC_RELAXED,
                                     __HIP_MEMORY_SCOPE_AGENT) < r - 1)
                __builtin_amdgcn_s_sleep(1);
            seen = __hip_atomic_load(&flags[tid], __ATOMIC_ACQUIRE,
                                     __HIP_MEMORY_SCOPE_AGENT);
        }
        __syncthreads();   // B2

        // -- fresh-child dots, direct from global
        for (int s = 0; s < fc; ++s) {
            const int pk = slots_s[ss + oc + s];
            const int j = pk & 0xFFF, n = pk >> 12;
            const float* hrow = out + (size_t)j * HH + lane32;
            float d0 = 0.0f, d1 = 0.0f, d2 = 0.0f, d3 = 0.0f;
            #pragma unroll
            for (int q = 0; q < 32; ++q) {
                const float hv = __hip_atomic_load(hrow + 32 * q, __ATOMIC_RELAXED,
                                                   __HIP_MEMORY_SCOPE_AGENT);
                d0 += w_i[q] * hv; d1 += w_o[q] * hv;
                d2 += w_u[q] * hv; d3 += w_f[q] * hv;
            }
            #pragma unroll
            for (int o2 = 16; o2 > 0; o2 >>= 1) {
                d0 += __shfl_down(d0, o2, 32); d1 += __shfl_down(d1, o2, 32);
                d2 += __shfl_down(d2, o2, 32); d3 += __shfl_down(d3, o2, 32);
            }
            if (lane32 == 0) {
                dpart[pb][n][0][e_loc] += d0;
                dpart[pb][n][1][e_loc] += d1;
                dpart[pb][n][2][e_loc] += d2;
                dpart[pb][n][3][e_loc] +=
                    sigmoidf_(gx_st[pb][n][3][e_loc] + d3 + bhf)
                    * c_all[j * 8 + e_loc];
            }
        }
        __syncthreads();   // B3: dpart complete

        // -- gates on wave0 only; slim publish (no full-WG barrier)
        if (tid < 64) {
            if (tid < nc * 8) {
                const int n = tid >> 3, e = tid & 7;
                const int t = order_s[ns + n];
                const float iv = sigmoidf_(gx_st[pb][n][0][e] + dpart[pb][n][0][e] + bh_s[0][e]);
                const float ov = sigmoidf_(gx_st[pb][n][1][e] + dpart[pb][n][1][e] + bh_s[1][e]);
                const float uv = tanhf    (gx_st[pb][n][2][e] + dpart[pb][n][2][e] + bh_s[2][e]);
                const float c  = iv * uv + dpart[pb][n][3][e];
                const float h  = ov * tanhf(c);
                c_all[t * 8 + e] = c;
                __hip_atomic_store(out + (size_t)t * HH + b * 8 + e, h,
                                   __ATOMIC_RELAXED, __HIP_MEMORY_SCOPE_AGENT);
                if (t == NN - 1) {
                    __hip_atomic_store(out + (size_t)NN * HH + b * 8 + e, c,
                                       __ATOMIC_RELAXED, __HIP_MEMORY_SCOPE_AGENT);
                    __hip_atomic_store(out + (size_t)NN * HH + HH + b * 8 + e, h,
                                       __ATOMIC_RELAXED, __HIP_MEMORY_SCOPE_AGENT);
                }
            }
            // wave-shared vmcnt covers all wave0 lanes' h stores
            asm volatile("s_waitcnt vmcnt(0)" ::: "memory");
            if (tid == 0 && lastb)
                __hip_atomic_store(&flags[b], r, __ATOMIC_RELEASE,
                                   __HIP_MEMORY_SCOPE_AGENT);
        }
        // no barrier: waves 1-3 proceed to next batch's phase A (buffer pb^1)
        pb ^= 1;
    }
}

// ---------------------------------------------------------------- launch
extern "C" void kernel_launch(void* const* d_in, const int* in_sizes, int n_in,
                              void* d_out, int out_size, void* d_ws, size_t ws_size,
                              hipStream_t stream)
{
    const int*   inputs = (const int*)d_in[0];
    const int*   parent = (const int*)d_in[1];
    const float* emb    = (const float*)d_in[2];
    const float* Wx     = (const float*)d_in[3];
    const float* bx     = (const float*)d_in[4];
    const float* Wh     = (const float*)d_in[5];
    const float* bh     = (const float*)d_in[6];
    float* out = (float*)d_out;          // fp32 output (reference is fp32)

    char* ws = (char*)d_ws;
    int*  flags = (int*)ws;                                     // 512 B
    unsigned short* gx = (unsigned short*)(ws + 1024);          // 16 MB bf16
    char* ws2 = ws + 1024 + (size_t)NN * MM * 2;
    int*  order = (int*)ws2;                                    // 8 KB
    int*  meta  = (int*)(ws2 + 8192);                           // 64 B
    int*  bhdr  = (int*)(ws2 + 8192 + 64);                      // 16 KB
    int*  slots = (int*)(ws2 + 8192 + 64 + 16384);              // 8 KB

    // dynamic LDS: c_all 64 KB (static ~36.5 KB => ~100.5 KB total)
    hipFuncSetAttribute(reinterpret_cast<const void*>(lstm_scan),
                        hipFuncAttributeMaxDynamicSharedMemorySize, 65536);

    hipLaunchKernelGGL(init_flags, dim3(1), dim3(128), 0, stream, flags);
    hipLaunchKernelGGL(build_sched, dim3(1), dim3(TPB), 0, stream,
                       parent, order, meta, bhdr, slots);
    hipLaunchKernelGGL(gx_gemm, dim3(MM / 64, NN / 64), dim3(256), 0, stream,
                       inputs, emb, Wx, bx, gx);
    hipLaunchKernelGGL(lstm_scan, dim3(NWG), dim3(TPB), 65536, stream,
                       Wh, bh, gx, order, meta, bhdr, slots, flags, out);
}